// Round 5
// baseline (206.761 us; speedup 1.0000x reference)
//
#include <hip/hip_runtime.h>
#include <cstdint>
#include <cstddef>

// ---------- types ----------
typedef __attribute__((ext_vector_type(8))) short  bf16x8;   // MFMA bf16 A/B frag (K=32)
typedef __attribute__((ext_vector_type(8))) _Float16 f16x8;  // 16B LDS read / f16 K=32 frag
typedef __attribute__((ext_vector_type(4))) _Float16 f16x4;  // half of a K=32 A frag
typedef __attribute__((ext_vector_type(4))) float  f32x4;    // MFMA C/D frag
typedef __attribute__((ext_vector_type(4))) unsigned short u16x4;
typedef __attribute__((ext_vector_type(2))) unsigned int u32x2;

#define LOG2E 1.44269504088896340736f
#define PBIAS 6.0f   // softmax shift (cancels in normalization); keeps 2^t in f16 range

__device__ __forceinline__ unsigned short f2bf(float f) {
  unsigned int u = __builtin_bit_cast(unsigned int, f);
  u += 0x7fffu + ((u >> 16) & 1u);
  return (unsigned short)(u >> 16);
}
__device__ __forceinline__ float bf2f(unsigned short s) {
  unsigned int u = ((unsigned int)s) << 16;
  return __builtin_bit_cast(float, u);
}

// single v_exp_f32 via compiler intrinsic (hazards handled; inputs bounded here)
__device__ __forceinline__ float fast_exp2(float x) {
  return __builtin_amdgcn_exp2f(x);
}

// async global->LDS, 16B per lane (wave-uniform LDS base + lane*16)
__device__ __forceinline__ void gll16(const void* g, void* l) {
  __builtin_amdgcn_global_load_lds(
      (const __attribute__((address_space(1))) unsigned int*)g,
      (__attribute__((address_space(3))) unsigned int*)l, 16, 0, 0);
}

// ---------- fused prep: cvt x (blk<4096), cvt Wo (<5120), 4x transpose (<6144) ----------
__global__ __launch_bounds__(256) void prep(
    const float* __restrict__ x,  unsigned short* __restrict__ xb,
    const float* __restrict__ Wo, unsigned short* __restrict__ Wob,
    const float* __restrict__ R,  const float* __restrict__ Wq,
    const float* __restrict__ Wk, const float* __restrict__ Wv,
    unsigned short* __restrict__ RT,  unsigned short* __restrict__ WqT,
    unsigned short* __restrict__ WkT, unsigned short* __restrict__ WvT) {
  int bid = blockIdx.x;
  __shared__ unsigned short s[64][68];
  if (bid < 5120) {
    const float* src = bid < 4096 ? x : Wo;
    unsigned short* dst = bid < 4096 ? xb : Wob;
    int i = (bid < 4096 ? bid : bid - 4096) * 256 + threadIdx.x;
    float4 v = ((const float4*)src)[i];
    u16x4 o;
    o[0] = f2bf(v.x); o[1] = f2bf(v.y); o[2] = f2bf(v.z); o[3] = f2bf(v.w);
    ((u16x4*)dst)[i] = o;
    return;
  }
  int t = bid - 5120;
  int z = t >> 8, tile = t & 255;
  const float* in = z == 0 ? R : (z == 1 ? Wq : (z == 2 ? Wk : Wv));
  unsigned short* out = z == 0 ? RT : (z == 1 ? WqT : (z == 2 ? WkT : WvT));
  int r0 = (tile >> 4) * 64, c0 = (tile & 15) * 64;
  int tt = threadIdx.x;
  int tr = tt >> 4, tc4 = (tt & 15) * 4;
  for (int i = 0; i < 4; ++i) {
    int r = tr + i * 16;
    float4 v = *(const float4*)(in + (size_t)(r0 + r) * 1024 + c0 + tc4);
    s[r][tc4 + 0] = f2bf(v.x); s[r][tc4 + 1] = f2bf(v.y);
    s[r][tc4 + 2] = f2bf(v.z); s[r][tc4 + 3] = f2bf(v.w);
  }
  __syncthreads();
  for (int i = 0; i < 4; ++i) {
    int oc = tr + i * 16;
    u16x4 o;
    o[0] = s[tc4 + 0][oc]; o[1] = s[tc4 + 1][oc];
    o[2] = s[tc4 + 2][oc]; o[3] = s[tc4 + 3][oc];
    *(u16x4*)(out + (size_t)(c0 + oc) * 1024 + r0 + tc4) = o;
  }
}

// ---------- transpose V: bf16 [4096][1024] -> f16 [1024][4096], kv-permuted ----------
__global__ void tr_v(const unsigned short* __restrict__ in, unsigned short* __restrict__ out) {
  __shared__ unsigned short s[64][68];
  int t = threadIdx.x;
  int r0 = blockIdx.y * 64, c0 = blockIdx.x * 64;
  int tr = t >> 4, tc4 = (t & 15) * 4;
  for (int i = 0; i < 4; ++i) {
    int r = tr + i * 16;
    u16x4 v = *(const u16x4*)(in + (size_t)(r0 + r) * 1024 + c0 + tc4);
    s[r][tc4 + 0] = v[0]; s[r][tc4 + 1] = v[1]; s[r][tc4 + 2] = v[2]; s[r][tc4 + 3] = v[3];
  }
  __syncthreads();
  for (int i = 0; i < 4; ++i) {
    int oc = tr + i * 16;
    u16x4 o;
#pragma unroll
    for (int j = 0; j < 4; ++j) {
      _Float16 h = (_Float16)bf2f(s[tc4 + j][oc]);
      o[j] = __builtin_bit_cast(unsigned short, h);
    }
    int col = r0 + tc4;                       // kv of first of the 4 consecutive
    int c32 = col & 31;
    int pos = (col & ~31) + ((c32 >> 2) & 3) * 8 + (c32 >> 4) * 4;
    *(u16x4*)(out + (size_t)(c0 + oc) * 4096 + pos) = o;
  }
}

// ---------- NT GEMM v2: C[M][N] = A[M][K]*B[N][K]^T, 128x128 tile, BK=64 ----------
// Double-buffered prefetch (barrier -> stage(k+1) -> compute(k)). SWAP transposes
// the grid (x=m-tile) so XCD = m-tile%8: A slice (1MB) + B (2MB) become
// L2-resident per XCD for the gemm3 shape (32,8,1).
template <bool BF16OUT, bool SWAP>
__global__ __launch_bounds__(256) void gemm_nt(
    const unsigned short* __restrict__ A,
    const unsigned short* __restrict__ B0, const unsigned short* __restrict__ B1,
    const unsigned short* __restrict__ B2,
    void* __restrict__ C0, void* __restrict__ C1, void* __restrict__ C2,
    int M, int N, int K) {
  const unsigned short* B = blockIdx.z == 0 ? B0 : (blockIdx.z == 1 ? B1 : B2);
  void* Cv = blockIdx.z == 0 ? C0 : (blockIdx.z == 1 ? C1 : C2);

  __shared__ unsigned short As[2][128 * 64];
  __shared__ unsigned short Bs[2][128 * 64];

  int tid = threadIdx.x, w = tid >> 6, lane = tid & 63;
  int lo = lane & 15, quad = lane >> 4;
  int m0 = (SWAP ? blockIdx.x : blockIdx.y) * 128;
  int n0 = (SWAP ? blockIdx.y : blockIdx.x) * 128;
  int wm = (w >> 1) * 64, wn = (w & 1) * 64;

  f32x4 z4 = {0.f, 0.f, 0.f, 0.f};
  f32x4 acc[4][4];
  for (int mi = 0; mi < 4; ++mi)
    for (int ni = 0; ni < 4; ++ni) acc[mi][ni] = z4;

  int rloc = lane >> 3;
  int srcChunk = (lane & 7) ^ (rloc & 7);
  int cbase = w * 4;
  const unsigned short* Ag = A + (size_t)(m0 + cbase * 8 + rloc) * K + srcChunk * 8;
  const unsigned short* Bg = B + (size_t)(n0 + cbase * 8 + rloc) * K + srcChunk * 8;
  int ldsOfs = cbase * 512 + lane * 8;
  int cx0 = (quad ^ (lane & 7)) * 8;
  int cx1 = ((quad + 4) ^ (lane & 7)) * 8;

  // stage k-tile 0 into buffer 0
#pragma unroll
  for (int j = 0; j < 4; ++j) {
    gll16(Ag + (size_t)j * 8 * K, As[0] + ldsOfs + j * 512);
    gll16(Bg + (size_t)j * 8 * K, Bs[0] + ldsOfs + j * 512);
  }

  int nk = K >> 6;
  for (int kt = 0; kt < nk; ++kt) {
    int buf = kt & 1;
    __syncthreads();   // drains stage(kt) (issued one full compute phase ago)
    if (kt + 1 < nk) {
      int k0 = (kt + 1) << 6;
#pragma unroll
      for (int j = 0; j < 4; ++j) {
        gll16(Ag + (size_t)j * 8 * K + k0, As[buf ^ 1] + ldsOfs + j * 512);
        gll16(Bg + (size_t)j * 8 * K + k0, Bs[buf ^ 1] + ldsOfs + j * 512);
      }
    }
    const unsigned short* Ab = As[buf];
    const unsigned short* Bb = Bs[buf];
#pragma unroll
    for (int ks = 0; ks < 2; ++ks) {
      int cx = ks ? cx1 : cx0;
      bf16x8 af[4], bfr[4];
#pragma unroll
      for (int mi = 0; mi < 4; ++mi)
        af[mi] = *(const bf16x8*)(Ab + (wm + mi * 16 + lo) * 64 + cx);
#pragma unroll
      for (int ni = 0; ni < 4; ++ni)
        bfr[ni] = *(const bf16x8*)(Bb + (wn + ni * 16 + lo) * 64 + cx);
#pragma unroll
      for (int mi = 0; mi < 4; ++mi)
#pragma unroll
        for (int ni = 0; ni < 4; ++ni)
          acc[mi][ni] = __builtin_amdgcn_mfma_f32_16x16x32_bf16(af[mi], bfr[ni], acc[mi][ni], 0, 0, 0);
    }
  }

#pragma unroll
  for (int mi = 0; mi < 4; ++mi)
#pragma unroll
    for (int ni = 0; ni < 4; ++ni)
      for (int i = 0; i < 4; ++i) {
        int r = m0 + wm + mi * 16 + quad * 4 + i;
        int c = n0 + wn + ni * 16 + lo;
        if (BF16OUT)
          ((unsigned short*)Cv)[(size_t)r * N + c] = f2bf(acc[mi][ni][i]);
        else
          ((float*)Cv)[(size_t)r * N + c] = acc[mi][ni][i];
      }
}

// ---------- fused QKV GEMM: {Q,K,V}[M][N] = A[M][K] * B{0,1,2}[N][K]^T ----------
// The three QKV GEMMs share A (xb): one block computes the 128x128 tile of ALL
// THREE outputs, so each staged A-byte feeds 3x the MFMAs and the per-iter
// compute phase (~96 MFMA + 128 ds_read_b128/CU ~ 1000 cy) exceeds the load
// latency -> the 1-deep prefetch fully hides it (the split version exposed
// ~600 cy/iter: MfmaUtil 21%). Grid (32 m-tiles, 8 n-tiles) = 256 blocks =
// 1/CU exactly; XCD = m-tile%8 -> per-K-step working set (A slice 64KB +
// all-B K-slices 384KB) is L2-hot, B panels get 4x L2 reuse.
// LDS 128KB dbuf (1 block/CU by grid anyway). acc[3][4][4] -> ~250 VGPR at
// launch_bounds(256,1) (512/wave budget, no spill through 450 per m08/m24).
__global__ __launch_bounds__(256, 1) void gemm_qkv(
    const unsigned short* __restrict__ A,
    const unsigned short* __restrict__ B0, const unsigned short* __restrict__ B1,
    const unsigned short* __restrict__ B2,
    unsigned short* __restrict__ C0, unsigned short* __restrict__ C1,
    unsigned short* __restrict__ C2,
    int M, int N, int K) {
  __shared__ unsigned short As[2][128 * 64];
  __shared__ unsigned short Bs[2][3][128 * 64];

  int tid = threadIdx.x, w = tid >> 6, lane = tid & 63;
  int lo = lane & 15, quad = lane >> 4;
  int m0 = blockIdx.x * 128, n0 = blockIdx.y * 128;
  int wm = (w >> 1) * 64, wn = (w & 1) * 64;

  f32x4 z4 = {0.f, 0.f, 0.f, 0.f};
  f32x4 acc[3][4][4];
#pragma unroll
  for (int z = 0; z < 3; ++z)
#pragma unroll
    for (int mi = 0; mi < 4; ++mi)
#pragma unroll
      for (int ni = 0; ni < 4; ++ni) acc[z][mi][ni] = z4;

  int rloc = lane >> 3;
  int srcChunk = (lane & 7) ^ (rloc & 7);
  int cbase = w * 4;
  const unsigned short* Ag = A + (size_t)(m0 + cbase * 8 + rloc) * K + srcChunk * 8;
  size_t bofs = (size_t)(n0 + cbase * 8 + rloc) * K + srcChunk * 8;
  const unsigned short* Bg0 = B0 + bofs;
  const unsigned short* Bg1 = B1 + bofs;
  const unsigned short* Bg2 = B2 + bofs;
  int ldsOfs = cbase * 512 + lane * 8;
  int cx0 = (quad ^ (lane & 7)) * 8;
  int cx1 = ((quad + 4) ^ (lane & 7)) * 8;

  // stage k-tile 0 into buffer 0
#pragma unroll
  for (int j = 0; j < 4; ++j) {
    gll16(Ag  + (size_t)j * 8 * K, As[0]    + ldsOfs + j * 512);
    gll16(Bg0 + (size_t)j * 8 * K, Bs[0][0] + ldsOfs + j * 512);
    gll16(Bg1 + (size_t)j * 8 * K, Bs[0][1] + ldsOfs + j * 512);
    gll16(Bg2 + (size_t)j * 8 * K, Bs[0][2] + ldsOfs + j * 512);
  }

  int nk = K >> 6;
  for (int kt = 0; kt < nk; ++kt) {
    int buf = kt & 1;
    __syncthreads();   // drains stage(kt) (issued one full compute phase ago)
    if (kt + 1 < nk) {
      int k0 = (kt + 1) << 6;
#pragma unroll
      for (int j = 0; j < 4; ++j) {
        gll16(Ag  + (size_t)j * 8 * K + k0, As[buf ^ 1]    + ldsOfs + j * 512);
        gll16(Bg0 + (size_t)j * 8 * K + k0, Bs[buf ^ 1][0] + ldsOfs + j * 512);
        gll16(Bg1 + (size_t)j * 8 * K + k0, Bs[buf ^ 1][1] + ldsOfs + j * 512);
        gll16(Bg2 + (size_t)j * 8 * K + k0, Bs[buf ^ 1][2] + ldsOfs + j * 512);
      }
    }
    const unsigned short* Ab = As[buf];
#pragma unroll
    for (int ks = 0; ks < 2; ++ks) {
      int cx = ks ? cx1 : cx0;
      bf16x8 af[4];
#pragma unroll
      for (int mi = 0; mi < 4; ++mi)
        af[mi] = *(const bf16x8*)(Ab + (wm + mi * 16 + lo) * 64 + cx);
#pragma unroll
      for (int z = 0; z < 3; ++z) {
        const unsigned short* Bb = Bs[buf][z];
        bf16x8 bfr[4];
#pragma unroll
        for (int ni = 0; ni < 4; ++ni)
          bfr[ni] = *(const bf16x8*)(Bb + (wn + ni * 16 + lo) * 64 + cx);
#pragma unroll
        for (int mi = 0; mi < 4; ++mi)
#pragma unroll
          for (int ni = 0; ni < 4; ++ni)
            acc[z][mi][ni] = __builtin_amdgcn_mfma_f32_16x16x32_bf16(af[mi], bfr[ni], acc[z][mi][ni], 0, 0, 0);
      }
    }
  }

  unsigned short* Cz0 = C0; unsigned short* Cz1 = C1; unsigned short* Cz2 = C2;
#pragma unroll
  for (int z = 0; z < 3; ++z) {
    unsigned short* Cv = z == 0 ? Cz0 : (z == 1 ? Cz1 : Cz2);
#pragma unroll
    for (int mi = 0; mi < 4; ++mi)
#pragma unroll
      for (int ni = 0; ni < 4; ++ni)
#pragma unroll
        for (int i = 0; i < 4; ++i) {
          int r = m0 + wm + mi * 16 + quad * 4 + i;
          int c = n0 + wn + ni * 16 + lo;
          Cv[(size_t)r * N + c] = f2bf(acc[z][mi][ni][i]);
        }
  }
}

// ---------- flash attention v13: block-internal KV split (8 waves, 2 halves) ----------
__global__ __launch_bounds__(512, 4) void flash_attn(
    const unsigned short* __restrict__ Q, const unsigned short* __restrict__ Kg_,
    const unsigned short* __restrict__ Vt, const float* __restrict__ ent,
    unsigned short* __restrict__ O) {
  int tid = threadIdx.x, w = tid >> 6, lane = tid & 63;
  int lo = lane & 15, quad = lane >> 4;
  int half = w >> 2, wl = w & 3;             // KV-half, wave-within-half

  int bid = blockIdx.x;
  int g = (bid & 7) + 8 * (bid >> 7);        // (b,h) group: id%8 fixed per group
  int qt = (bid >> 3) & 15;                  // q-tile (128 rows) within group
  int b = g >> 4, h = g & 15;
  int q0 = qt * 128;
  float scale = ent[h] * (0.125f * LOG2E);

  // 64 KB: K region [half][buf] at (half*2+buf)*4096, V region at +16384 (ushorts)
  __shared__ unsigned short lds[32768];

  // Q fragments (B-operand of S^T), scale folded in. 32 q rows/wave = 2 frag sets.
  bf16x8 aq[2][2];                             // [f][ks]
#pragma unroll
  for (int f = 0; f < 2; ++f)
#pragma unroll
    for (int ks = 0; ks < 2; ++ks) {
      uint4 v = *(const uint4*)(Q + (size_t)(b * 2048 + q0 + wl * 32 + f * 16 + lo) * 1024 +
                                h * 64 + ks * 32 + quad * 8);
      unsigned int* pv = (unsigned int*)&v;
      uint4 o; unsigned int* po = (unsigned int*)&o;
#pragma unroll
      for (int j = 0; j < 4; ++j) {
        float f0 = bf2f((unsigned short)(pv[j] & 0xffffu)) * scale;
        float f1 = bf2f((unsigned short)(pv[j] >> 16)) * scale;
        po[j] = (unsigned int)f2bf(f0) | ((unsigned int)f2bf(f1) << 16);
      }
      aq[f][ks] = *(bf16x8*)&o;
    }

  f32x4 binit = {-PBIAS, -PBIAS, -PBIAS, -PBIAS};
  f32x4 z4 = {0.f, 0.f, 0.f, 0.f};
  f32x4 acco[4][2];                            // [di][f]
#pragma unroll
  for (int di = 0; di < 4; ++di) {
    acco[di][0] = z4; acco[di][1] = z4;
  }
  float lsum0 = 0.f, lsum1 = 0.f;

  int rloc = lane >> 3;
  int srcChunk = (lane & 7) ^ (rloc & 7);
  int cb = wl * 2;                           // 4 waves/half cover 8 chunks per matrix
  const unsigned short* Kp = Kg_ + (size_t)(b * 2048 + half * 1024) * 1024 + h * 64;
  const unsigned short* Vp = Vt + (size_t)(h * 64) * 4096 + (size_t)(b * 2048 + half * 1024);
  int cx0 = (quad ^ (lane & 7)) * 8;
  int cx1 = ((quad + 4) ^ (lane & 7)) * 8;

  unsigned short* Kh = lds + half * 2 * 4096;
  unsigned short* Vh = lds + 16384 + half * 2 * 4096;

  // stage tile 0 into buffer 0 (per half)
#pragma unroll
  for (int j = 0; j < 2; ++j) {
    int c = cb + j;
    int r = c * 8 + rloc;
    gll16(Kp + (size_t)r * 1024 + srcChunk * 8, Kh + c * 512 + lane * 8);
    gll16(Vp + (size_t)r * 4096 + srcChunk * 8, Vh + c * 512 + lane * 8);
  }

  for (int it = 0; it < 16; ++it) {
    int buf = it & 1;
    __syncthreads();   // drains this tile's staging (issued one full tile ago)
    if (it + 1 < 16) {
      int kvn = (it + 1) * 64;
#pragma unroll
      for (int j = 0; j < 2; ++j) {
        int c = cb + j;
        int r = c * 8 + rloc;
        gll16(Kp + (size_t)(kvn + r) * 1024 + srcChunk * 8, Kh + (buf ^ 1) * 4096 + c * 512 + lane * 8);
        gll16(Vp + (size_t)r * 4096 + kvn + srcChunk * 8, Vh + (buf ^ 1) * 4096 + c * 512 + lane * 8);
      }
    }
    const unsigned short* Kb_ = Kh + buf * 4096;
    const unsigned short* Vb_ = Vh + buf * 4096;

    // S^T = K.Q^T : C[m=kv][n=q]; bias -PBIAS folded into the C-init (free).
    f32x4 accs[4][2];
    __builtin_amdgcn_s_setprio(1);
#pragma unroll
    for (int kt = 0; kt < 4; ++kt) {
      bf16x8 kf0 = *(const bf16x8*)(Kb_ + (kt * 16 + lo) * 64 + cx0);
      bf16x8 kf1 = *(const bf16x8*)(Kb_ + (kt * 16 + lo) * 64 + cx1);
#pragma unroll
      for (int f = 0; f < 2; ++f) {
        f32x4 a = __builtin_amdgcn_mfma_f32_16x16x32_bf16(kf0, aq[f][0], binit, 0, 0, 0);
        accs[kt][f] = __builtin_amdgcn_mfma_f32_16x16x32_bf16(kf1, aq[f][1], a, 0, 0, 0);
      }
    }
    __builtin_amdgcn_s_setprio(0);

    // P' = 2^(S^T - bias): registers hold P[q=lo][kv] == f16 A-frag layout
    f16x4 ap[4][2];
#pragma unroll
    for (int kt = 0; kt < 4; ++kt) {
#pragma unroll
      for (int f = 0; f < 2; ++f) {
        float p0 = fast_exp2(accs[kt][f][0]);
        float p1 = fast_exp2(accs[kt][f][1]);
        float p2 = fast_exp2(accs[kt][f][2]);
        float p3 = fast_exp2(accs[kt][f][3]);
        if (f == 0) lsum0 += (p0 + p1) + (p2 + p3);
        else        lsum1 += (p0 + p1) + (p2 + p3);
        u32x2 uu;
        uu[0] = __builtin_bit_cast(unsigned int, __builtin_amdgcn_cvt_pkrtz(p0, p1));
        uu[1] = __builtin_bit_cast(unsigned int, __builtin_amdgcn_cvt_pkrtz(p2, p3));
        ap[kt][f] = __builtin_bit_cast(f16x4, uu);
      }
    }

    // O += P.V via f16 16x16x32 MFMA; one b128 V read feeds both q-fragments.
    __builtin_amdgcn_s_setprio(1);
#pragma unroll
    for (int t2 = 0; t2 < 2; ++t2) {
      f16x8 a80 = __builtin_shufflevector(ap[2 * t2][0], ap[2 * t2 + 1][0], 0, 1, 2, 3, 4, 5, 6, 7);
      f16x8 a81 = __builtin_shufflevector(ap[2 * t2][1], ap[2 * t2 + 1][1], 0, 1, 2, 3, 4, 5, 6, 7);
#pragma unroll
      for (int di = 0; di < 4; ++di) {
        f16x8 bv8 = *(const f16x8*)(Vb_ + (di * 16 + lo) * 64 +
                                    (((t2 * 4 + quad) ^ (lo & 7)) << 3));
        acco[di][0] = __builtin_amdgcn_mfma_f32_16x16x32_f16(a80, bv8, acco[di][0], 0, 0, 0);
        acco[di][1] = __builtin_amdgcn_mfma_f32_16x16x32_f16(a81, bv8, acco[di][1], 0, 0, 0);
      }
    }
    __builtin_amdgcn_s_setprio(0);
  }

  // ---- combine the two KV halves (partial sums are exactly additive) ----
  __syncthreads();                         // all waves done with staging LDS
  float* cm = (float*)lds;                 // 16384 floats available
  float* base = cm + wl * 2304;            // 36 slots x 64 lanes per wl
  if (half == 1) {
#pragma unroll
    for (int di = 0; di < 4; ++di)
#pragma unroll
      for (int f = 0; f < 2; ++f)
#pragma unroll
        for (int i = 0; i < 4; ++i)
          base[(di * 8 + f * 4 + i) * 64 + lane] = acco[di][f][i];
    base[32 * 64 + lane] = lsum0;
    base[33 * 64 + lane] = lsum1;
  }
  __syncthreads();
  if (half == 1) return;

#pragma unroll
  for (int di = 0; di < 4; ++di)
#pragma unroll
    for (int f = 0; f < 2; ++f)
#pragma unroll
      for (int i = 0; i < 4; ++i)
        acco[di][f][i] += base[(di * 8 + f * 4 + i) * 64 + lane];
  lsum0 += base[32 * 64 + lane];
  lsum1 += base[33 * 64 + lane];

  // row sum for q=lo spread over quads -> 2 shuffles; per q-fragment
#pragma unroll
  for (int f = 0; f < 2; ++f) {
    float v = f == 0 ? lsum0 : lsum1;
    v += __shfl_xor(v, 16);
    v += __shfl_xor(v, 32);
    float inv = 1.0f / v;

#pragma unroll
    for (int i = 0; i < 4; ++i) {
      float invq = __shfl(inv, quad * 4 + i);
#pragma unroll
      for (int di = 0; di < 4; ++di) {
        size_t ofs = (size_t)(b * 2048 + q0 + wl * 32 + f * 16 + quad * 4 + i) * 1024 +
                     h * 64 + di * 16 + lo;
        O[ofs] = f2bf(acco[di][f][i] * invq);
      }
    }
  }
}

// ---------- launch ----------
extern "C" void kernel_launch(void* const* d_in, const int* in_sizes, int n_in,
                              void* d_out, int out_size, void* d_ws, size_t ws_size,
                              hipStream_t stream) {
  const float* x   = (const float*)d_in[0];
  const float* R   = (const float*)d_in[1];
  const float* ent = (const float*)d_in[2];
  const float* Wq  = (const float*)d_in[3];
  const float* Wk  = (const float*)d_in[4];
  const float* Wv  = (const float*)d_in[5];
  const float* Wo  = (const float*)d_in[6];
  float* out = (float*)d_out;

  const size_t MLD = (size_t)4096 * 1024;
  const size_t DD  = (size_t)1024 * 1024;
  if (ws_size < (MLD * 6 + DD * 8) * 2) return;

  unsigned short* ws  = (unsigned short*)d_ws;
  unsigned short* xb  = ws;
  unsigned short* RT  = xb + MLD;
  unsigned short* WqT = RT + DD;
  unsigned short* WkT = WqT + DD;
  unsigned short* WvT = WkT + DD;
  unsigned short* Wob = WvT + DD;
  unsigned short* AqT = Wob + DD;
  unsigned short* AkT = AqT + DD;
  unsigned short* AvT = AkT + DD;
  unsigned short* Qb  = AvT + DD;
  unsigned short* Kb  = Qb + MLD;
  unsigned short* Vb  = Kb + MLD;
  unsigned short* Vtf = Vb + MLD;   // V^T as f16 [1024][4096], kv-permuted
  unsigned short* aO  = Vtf + MLD;

  // fused converts + weight transposes (one launch)
  prep<<<dim3(6144), dim3(256), 0, stream>>>(
      x, xb, Wo, Wob, R, Wq, Wk, Wv, RT, WqT, WkT, WvT);

  // A*T = NT(RT, W*T) = R^T W* = (W*^T R)^T
  gemm_nt<true, false><<<dim3(8, 8, 3), dim3(256), 0, stream>>>(
      RT, WqT, WkT, WvT, (void*)AqT, (void*)AkT, (void*)AvT, 1024, 1024, 1024);
  // Q/K/V = NT(xb, A*T) -- fused over the 3 weight matrices (shared A tile)
  gemm_qkv<<<dim3(32, 8), dim3(256), 0, stream>>>(
      xb, AqT, AkT, AvT, Qb, Kb, Vb, 4096, 1024, 1024);
  // V -> V^T (f16, kv-permuted)
  tr_v<<<dim3(16, 64), dim3(256), 0, stream>>>(Vb, Vtf);
  // attention
  flash_attn<<<dim3(512), dim3(512), 0, stream>>>(Qb, Kb, Vtf, ent, aO);
  // out = NT(aO, Wob) -> fp32; grid transposed (x=m-tile) for XCD L2 locality
  gemm_nt<false, true><<<dim3(32, 8, 1), dim3(256), 0, stream>>>(
      aO, Wob, Wob, Wob, (void*)out, (void*)out, (void*)out, 4096, 1024, 1024);
}

// Round 7
// 202.189 us; speedup vs baseline: 1.0226x; 1.0226x over previous
//
#include <hip/hip_runtime.h>
#include <cstdint>
#include <cstddef>

// ---------- types ----------
typedef __attribute__((ext_vector_type(8))) short  bf16x8;   // MFMA bf16 A/B frag (K=32)
typedef __attribute__((ext_vector_type(8))) _Float16 f16x8;  // 16B LDS read / f16 K=32 frag
typedef __attribute__((ext_vector_type(4))) _Float16 f16x4;  // half of a K=32 A frag
typedef __attribute__((ext_vector_type(4))) float  f32x4;    // MFMA C/D frag
typedef __attribute__((ext_vector_type(4))) unsigned short u16x4;
typedef __attribute__((ext_vector_type(2))) unsigned int u32x2;

#define LOG2E 1.44269504088896340736f
#define PBIAS 6.0f   // softmax shift (cancels in normalization); keeps 2^t in f16 range

__device__ __forceinline__ unsigned short f2bf(float f) {
  unsigned int u = __builtin_bit_cast(unsigned int, f);
  u += 0x7fffu + ((u >> 16) & 1u);
  return (unsigned short)(u >> 16);
}
__device__ __forceinline__ float bf2f(unsigned short s) {
  unsigned int u = ((unsigned int)s) << 16;
  return __builtin_bit_cast(float, u);
}

// single v_exp_f32 via compiler intrinsic (hazards handled; inputs bounded here)
__device__ __forceinline__ float fast_exp2(float x) {
  return __builtin_amdgcn_exp2f(x);
}

// async global->LDS, 16B per lane (wave-uniform LDS base + lane*16)
__device__ __forceinline__ void gll16(const void* g, void* l) {
  __builtin_amdgcn_global_load_lds(
      (const __attribute__((address_space(1))) unsigned int*)g,
      (__attribute__((address_space(3))) unsigned int*)l, 16, 0, 0);
}

// ---------- fused prep: cvt x (blk<4096), cvt Wo (<5120), 4x transpose (<6144) ----------
__global__ __launch_bounds__(256) void prep(
    const float* __restrict__ x,  unsigned short* __restrict__ xb,
    const float* __restrict__ Wo, unsigned short* __restrict__ Wob,
    const float* __restrict__ R,  const float* __restrict__ Wq,
    const float* __restrict__ Wk, const float* __restrict__ Wv,
    unsigned short* __restrict__ RT,  unsigned short* __restrict__ WqT,
    unsigned short* __restrict__ WkT, unsigned short* __restrict__ WvT) {
  int bid = blockIdx.x;
  __shared__ unsigned short s[64][68];
  if (bid < 5120) {
    const float* src = bid < 4096 ? x : Wo;
    unsigned short* dst = bid < 4096 ? xb : Wob;
    int i = (bid < 4096 ? bid : bid - 4096) * 256 + threadIdx.x;
    float4 v = ((const float4*)src)[i];
    u16x4 o;
    o[0] = f2bf(v.x); o[1] = f2bf(v.y); o[2] = f2bf(v.z); o[3] = f2bf(v.w);
    ((u16x4*)dst)[i] = o;
    return;
  }
  int t = bid - 5120;
  int z = t >> 8, tile = t & 255;
  const float* in = z == 0 ? R : (z == 1 ? Wq : (z == 2 ? Wk : Wv));
  unsigned short* out = z == 0 ? RT : (z == 1 ? WqT : (z == 2 ? WkT : WvT));
  int r0 = (tile >> 4) * 64, c0 = (tile & 15) * 64;
  int tt = threadIdx.x;
  int tr = tt >> 4, tc4 = (tt & 15) * 4;
  for (int i = 0; i < 4; ++i) {
    int r = tr + i * 16;
    float4 v = *(const float4*)(in + (size_t)(r0 + r) * 1024 + c0 + tc4);
    s[r][tc4 + 0] = f2bf(v.x); s[r][tc4 + 1] = f2bf(v.y);
    s[r][tc4 + 2] = f2bf(v.z); s[r][tc4 + 3] = f2bf(v.w);
  }
  __syncthreads();
  for (int i = 0; i < 4; ++i) {
    int oc = tr + i * 16;
    u16x4 o;
    o[0] = s[tc4 + 0][oc]; o[1] = s[tc4 + 1][oc];
    o[2] = s[tc4 + 2][oc]; o[3] = s[tc4 + 3][oc];
    *(u16x4*)(out + (size_t)(c0 + oc) * 1024 + r0 + tc4) = o;
  }
}

// ---------- transpose V: bf16 [4096][1024] -> f16 [1024][4096], kv-permuted ----------
__global__ void tr_v(const unsigned short* __restrict__ in, unsigned short* __restrict__ out) {
  __shared__ unsigned short s[64][68];
  int t = threadIdx.x;
  int r0 = blockIdx.y * 64, c0 = blockIdx.x * 64;
  int tr = t >> 4, tc4 = (t & 15) * 4;
  for (int i = 0; i < 4; ++i) {
    int r = tr + i * 16;
    u16x4 v = *(const u16x4*)(in + (size_t)(r0 + r) * 1024 + c0 + tc4);
    s[r][tc4 + 0] = v[0]; s[r][tc4 + 1] = v[1]; s[r][tc4 + 2] = v[2]; s[r][tc4 + 3] = v[3];
  }
  __syncthreads();
  for (int i = 0; i < 4; ++i) {
    int oc = tr + i * 16;
    u16x4 o;
#pragma unroll
    for (int j = 0; j < 4; ++j) {
      _Float16 h = (_Float16)bf2f(s[tc4 + j][oc]);
      o[j] = __builtin_bit_cast(unsigned short, h);
    }
    int col = r0 + tc4;                       // kv of first of the 4 consecutive
    int c32 = col & 31;
    int pos = (col & ~31) + ((c32 >> 2) & 3) * 8 + (c32 >> 4) * 4;
    *(u16x4*)(out + (size_t)(c0 + oc) * 4096 + pos) = o;
  }
}

// ---------- NT GEMM v3: C[M][N] = A[M][K]*B[N][K]^T, 64x128 tile, BK=64 ----------
// R6's counted-vmcnt pipeline raced (m152: sync-structure edits need race screens
// we can't run here) -> reverted to the proven __syncthreads double-buffer and
// instead bought overlap via OCCUPANCY: 64x128 tile -> LDS 48 KB (As[2] 16K +
// Bs[2] 32K) -> 3 blocks/CU (12 waves/CU, the m97 regime). At 3 blocks/CU the
// per-block vmcnt(0)-before-barrier drain overlaps the other blocks' compute
// (m114) -- the race-free form of pipelining. All swizzle/staging geometry
// unchanged from the proven BK=64 code; A-staging uses flash's 64-row pattern
// (2 chunks/wave). grid.x = n-tile -> id%8 = XCD gets a fixed n-panel
// (256 KB/z, L2-resident); A streams via L3.
template <bool BF16OUT>
__global__ __launch_bounds__(256) void gemm_nt(
    const unsigned short* __restrict__ A,
    const unsigned short* __restrict__ B0, const unsigned short* __restrict__ B1,
    const unsigned short* __restrict__ B2,
    void* __restrict__ C0, void* __restrict__ C1, void* __restrict__ C2,
    int M, int N, int K) {
  const unsigned short* B = blockIdx.z == 0 ? B0 : (blockIdx.z == 1 ? B1 : B2);
  void* Cv = blockIdx.z == 0 ? C0 : (blockIdx.z == 1 ? C1 : C2);

  __shared__ unsigned short As[2][64 * 64];
  __shared__ unsigned short Bs[2][128 * 64];

  int tid = threadIdx.x, w = tid >> 6, lane = tid & 63;
  int lo = lane & 15, quad = lane >> 4;
  int m0 = blockIdx.y * 64, n0 = blockIdx.x * 128;
  int wm = (w >> 1) * 32, wn = (w & 1) * 64;

  f32x4 z4 = {0.f, 0.f, 0.f, 0.f};
  f32x4 acc[2][4];
  for (int mi = 0; mi < 2; ++mi)
    for (int ni = 0; ni < 4; ++ni) acc[mi][ni] = z4;

  int rloc = lane >> 3;
  int srcChunk = (lane & 7) ^ (rloc & 7);
  int acb = w * 2;                         // A: 4 waves cover 8 chunks (64 rows)
  int bcb = w * 4;                         // B: 4 waves cover 16 chunks (128 rows)
  const unsigned short* Ag = A + (size_t)(m0 + acb * 8 + rloc) * K + srcChunk * 8;
  const unsigned short* Bg = B + (size_t)(n0 + bcb * 8 + rloc) * K + srcChunk * 8;
  int ldsA = acb * 512 + lane * 8;
  int ldsB = bcb * 512 + lane * 8;
  int cx0 = (quad ^ (lane & 7)) * 8;
  int cx1 = ((quad + 4) ^ (lane & 7)) * 8;

  // stage k-tile 0 into buffer 0
#pragma unroll
  for (int j = 0; j < 2; ++j)
    gll16(Ag + (size_t)j * 8 * K, As[0] + ldsA + j * 512);
#pragma unroll
  for (int j = 0; j < 4; ++j)
    gll16(Bg + (size_t)j * 8 * K, Bs[0] + ldsB + j * 512);

  int nk = K >> 6;
  for (int kt = 0; kt < nk; ++kt) {
    int buf = kt & 1;
    __syncthreads();   // drains stage(kt) (issued one full compute phase ago)
    if (kt + 1 < nk) {
      int k0 = (kt + 1) << 6;
#pragma unroll
      for (int j = 0; j < 2; ++j)
        gll16(Ag + (size_t)j * 8 * K + k0, As[buf ^ 1] + ldsA + j * 512);
#pragma unroll
      for (int j = 0; j < 4; ++j)
        gll16(Bg + (size_t)j * 8 * K + k0, Bs[buf ^ 1] + ldsB + j * 512);
    }
    const unsigned short* Ab = As[buf];
    const unsigned short* Bb = Bs[buf];
#pragma unroll
    for (int ks = 0; ks < 2; ++ks) {
      int cx = ks ? cx1 : cx0;
      bf16x8 af[2], bfr[4];
#pragma unroll
      for (int mi = 0; mi < 2; ++mi)
        af[mi] = *(const bf16x8*)(Ab + (wm + mi * 16 + lo) * 64 + cx);
#pragma unroll
      for (int ni = 0; ni < 4; ++ni)
        bfr[ni] = *(const bf16x8*)(Bb + (wn + ni * 16 + lo) * 64 + cx);
#pragma unroll
      for (int mi = 0; mi < 2; ++mi)
#pragma unroll
        for (int ni = 0; ni < 4; ++ni)
          acc[mi][ni] = __builtin_amdgcn_mfma_f32_16x16x32_bf16(af[mi], bfr[ni], acc[mi][ni], 0, 0, 0);
    }
  }

#pragma unroll
  for (int mi = 0; mi < 2; ++mi)
#pragma unroll
    for (int ni = 0; ni < 4; ++ni)
      for (int i = 0; i < 4; ++i) {
        int r = m0 + wm + mi * 16 + quad * 4 + i;
        int c = n0 + wn + ni * 16 + lo;
        if (BF16OUT)
          ((unsigned short*)Cv)[(size_t)r * N + c] = f2bf(acc[mi][ni][i]);
        else
          ((float*)Cv)[(size_t)r * N + c] = acc[mi][ni][i];
      }
}

// ---------- flash attention v13: block-internal KV split (8 waves, 2 halves) ----------
__global__ __launch_bounds__(512, 4) void flash_attn(
    const unsigned short* __restrict__ Q, const unsigned short* __restrict__ Kg_,
    const unsigned short* __restrict__ Vt, const float* __restrict__ ent,
    unsigned short* __restrict__ O) {
  int tid = threadIdx.x, w = tid >> 6, lane = tid & 63;
  int lo = lane & 15, quad = lane >> 4;
  int half = w >> 2, wl = w & 3;             // KV-half, wave-within-half

  int bid = blockIdx.x;
  int g = (bid & 7) + 8 * (bid >> 7);        // (b,h) group: id%8 fixed per group
  int qt = (bid >> 3) & 15;                  // q-tile (128 rows) within group
  int b = g >> 4, h = g & 15;
  int q0 = qt * 128;
  float scale = ent[h] * (0.125f * LOG2E);

  // 64 KB: K region [half][buf] at (half*2+buf)*4096, V region at +16384 (ushorts)
  __shared__ unsigned short lds[32768];

  // Q fragments (B-operand of S^T), scale folded in. 32 q rows/wave = 2 frag sets.
  bf16x8 aq[2][2];                             // [f][ks]
#pragma unroll
  for (int f = 0; f < 2; ++f)
#pragma unroll
    for (int ks = 0; ks < 2; ++ks) {
      uint4 v = *(const uint4*)(Q + (size_t)(b * 2048 + q0 + wl * 32 + f * 16 + lo) * 1024 +
                                h * 64 + ks * 32 + quad * 8);
      unsigned int* pv = (unsigned int*)&v;
      uint4 o; unsigned int* po = (unsigned int*)&o;
#pragma unroll
      for (int j = 0; j < 4; ++j) {
        float f0 = bf2f((unsigned short)(pv[j] & 0xffffu)) * scale;
        float f1 = bf2f((unsigned short)(pv[j] >> 16)) * scale;
        po[j] = (unsigned int)f2bf(f0) | ((unsigned int)f2bf(f1) << 16);
      }
      aq[f][ks] = *(bf16x8*)&o;
    }

  f32x4 binit = {-PBIAS, -PBIAS, -PBIAS, -PBIAS};
  f32x4 z4 = {0.f, 0.f, 0.f, 0.f};
  f32x4 acco[4][2];                            // [di][f]
#pragma unroll
  for (int di = 0; di < 4; ++di) {
    acco[di][0] = z4; acco[di][1] = z4;
  }
  float lsum0 = 0.f, lsum1 = 0.f;

  int rloc = lane >> 3;
  int srcChunk = (lane & 7) ^ (rloc & 7);
  int cb = wl * 2;                           // 4 waves/half cover 8 chunks per matrix
  const unsigned short* Kp = Kg_ + (size_t)(b * 2048 + half * 1024) * 1024 + h * 64;
  const unsigned short* Vp = Vt + (size_t)(h * 64) * 4096 + (size_t)(b * 2048 + half * 1024);
  int cx0 = (quad ^ (lane & 7)) * 8;
  int cx1 = ((quad + 4) ^ (lane & 7)) * 8;

  unsigned short* Kh = lds + half * 2 * 4096;
  unsigned short* Vh = lds + 16384 + half * 2 * 4096;

  // stage tile 0 into buffer 0 (per half)
#pragma unroll
  for (int j = 0; j < 2; ++j) {
    int c = cb + j;
    int r = c * 8 + rloc;
    gll16(Kp + (size_t)r * 1024 + srcChunk * 8, Kh + c * 512 + lane * 8);
    gll16(Vp + (size_t)r * 4096 + srcChunk * 8, Vh + c * 512 + lane * 8);
  }

  for (int it = 0; it < 16; ++it) {
    int buf = it & 1;
    __syncthreads();   // drains this tile's staging (issued one full tile ago)
    if (it + 1 < 16) {
      int kvn = (it + 1) * 64;
#pragma unroll
      for (int j = 0; j < 2; ++j) {
        int c = cb + j;
        int r = c * 8 + rloc;
        gll16(Kp + (size_t)(kvn + r) * 1024 + srcChunk * 8, Kh + (buf ^ 1) * 4096 + c * 512 + lane * 8);
        gll16(Vp + (size_t)r * 4096 + kvn + srcChunk * 8, Vh + (buf ^ 1) * 4096 + c * 512 + lane * 8);
      }
    }
    const unsigned short* Kb_ = Kh + buf * 4096;
    const unsigned short* Vb_ = Vh + buf * 4096;

    // S^T = K.Q^T : C[m=kv][n=q]; bias -PBIAS folded into the C-init (free).
    f32x4 accs[4][2];
    __builtin_amdgcn_s_setprio(1);
#pragma unroll
    for (int kt = 0; kt < 4; ++kt) {
      bf16x8 kf0 = *(const bf16x8*)(Kb_ + (kt * 16 + lo) * 64 + cx0);
      bf16x8 kf1 = *(const bf16x8*)(Kb_ + (kt * 16 + lo) * 64 + cx1);
#pragma unroll
      for (int f = 0; f < 2; ++f) {
        f32x4 a = __builtin_amdgcn_mfma_f32_16x16x32_bf16(kf0, aq[f][0], binit, 0, 0, 0);
        accs[kt][f] = __builtin_amdgcn_mfma_f32_16x16x32_bf16(kf1, aq[f][1], a, 0, 0, 0);
      }
    }
    __builtin_amdgcn_s_setprio(0);

    // P' = 2^(S^T - bias): registers hold P[q=lo][kv] == f16 A-frag layout
    f16x4 ap[4][2];
#pragma unroll
    for (int kt = 0; kt < 4; ++kt) {
#pragma unroll
      for (int f = 0; f < 2; ++f) {
        float p0 = fast_exp2(accs[kt][f][0]);
        float p1 = fast_exp2(accs[kt][f][1]);
        float p2 = fast_exp2(accs[kt][f][2]);
        float p3 = fast_exp2(accs[kt][f][3]);
        if (f == 0) lsum0 += (p0 + p1) + (p2 + p3);
        else        lsum1 += (p0 + p1) + (p2 + p3);
        u32x2 uu;
        uu[0] = __builtin_bit_cast(unsigned int, __builtin_amdgcn_cvt_pkrtz(p0, p1));
        uu[1] = __builtin_bit_cast(unsigned int, __builtin_amdgcn_cvt_pkrtz(p2, p3));
        ap[kt][f] = __builtin_bit_cast(f16x4, uu);
      }
    }

    // O += P.V via f16 16x16x32 MFMA; one b128 V read feeds both q-fragments.
    __builtin_amdgcn_s_setprio(1);
#pragma unroll
    for (int t2 = 0; t2 < 2; ++t2) {
      f16x8 a80 = __builtin_shufflevector(ap[2 * t2][0], ap[2 * t2 + 1][0], 0, 1, 2, 3, 4, 5, 6, 7);
      f16x8 a81 = __builtin_shufflevector(ap[2 * t2][1], ap[2 * t2 + 1][1], 0, 1, 2, 3, 4, 5, 6, 7);
#pragma unroll
      for (int di = 0; di < 4; ++di) {
        f16x8 bv8 = *(const f16x8*)(Vb_ + (di * 16 + lo) * 64 +
                                    (((t2 * 4 + quad) ^ (lo & 7)) << 3));
        acco[di][0] = __builtin_amdgcn_mfma_f32_16x16x32_f16(a80, bv8, acco[di][0], 0, 0, 0);
        acco[di][1] = __builtin_amdgcn_mfma_f32_16x16x32_f16(a81, bv8, acco[di][1], 0, 0, 0);
      }
    }
    __builtin_amdgcn_s_setprio(0);
  }

  // ---- combine the two KV halves (partial sums are exactly additive) ----
  __syncthreads();                         // all waves done with staging LDS
  float* cm = (float*)lds;                 // 16384 floats available
  float* base = cm + wl * 2304;            // 36 slots x 64 lanes per wl
  if (half == 1) {
#pragma unroll
    for (int di = 0; di < 4; ++di)
#pragma unroll
      for (int f = 0; f < 2; ++f)
#pragma unroll
        for (int i = 0; i < 4; ++i)
          base[(di * 8 + f * 4 + i) * 64 + lane] = acco[di][f][i];
    base[32 * 64 + lane] = lsum0;
    base[33 * 64 + lane] = lsum1;
  }
  __syncthreads();
  if (half == 1) return;

#pragma unroll
  for (int di = 0; di < 4; ++di)
#pragma unroll
    for (int f = 0; f < 2; ++f)
#pragma unroll
      for (int i = 0; i < 4; ++i)
        acco[di][f][i] += base[(di * 8 + f * 4 + i) * 64 + lane];
  lsum0 += base[32 * 64 + lane];
  lsum1 += base[33 * 64 + lane];

  // row sum for q=lo spread over quads -> 2 shuffles; per q-fragment
#pragma unroll
  for (int f = 0; f < 2; ++f) {
    float v = f == 0 ? lsum0 : lsum1;
    v += __shfl_xor(v, 16);
    v += __shfl_xor(v, 32);
    float inv = 1.0f / v;

#pragma unroll
    for (int i = 0; i < 4; ++i) {
      float invq = __shfl(inv, quad * 4 + i);
#pragma unroll
      for (int di = 0; di < 4; ++di) {
        size_t ofs = (size_t)(b * 2048 + q0 + wl * 32 + f * 16 + quad * 4 + i) * 1024 +
                     h * 64 + di * 16 + lo;
        O[ofs] = f2bf(acco[di][f][i] * invq);
      }
    }
  }
}

// ---------- launch ----------
extern "C" void kernel_launch(void* const* d_in, const int* in_sizes, int n_in,
                              void* d_out, int out_size, void* d_ws, size_t ws_size,
                              hipStream_t stream) {
  const float* x   = (const float*)d_in[0];
  const float* R   = (const float*)d_in[1];
  const float* ent = (const float*)d_in[2];
  const float* Wq  = (const float*)d_in[3];
  const float* Wk  = (const float*)d_in[4];
  const float* Wv  = (const float*)d_in[5];
  const float* Wo  = (const float*)d_in[6];
  float* out = (float*)d_out;

  const size_t MLD = (size_t)4096 * 1024;
  const size_t DD  = (size_t)1024 * 1024;
  if (ws_size < (MLD * 6 + DD * 8) * 2) return;

  unsigned short* ws  = (unsigned short*)d_ws;
  unsigned short* xb  = ws;
  unsigned short* RT  = xb + MLD;
  unsigned short* WqT = RT + DD;
  unsigned short* WkT = WqT + DD;
  unsigned short* WvT = WkT + DD;
  unsigned short* Wob = WvT + DD;
  unsigned short* AqT = Wob + DD;
  unsigned short* AkT = AqT + DD;
  unsigned short* AvT = AkT + DD;
  unsigned short* Qb  = AvT + DD;
  unsigned short* Kb  = Qb + MLD;
  unsigned short* Vb  = Kb + MLD;
  unsigned short* Vtf = Vb + MLD;   // V^T as f16 [1024][4096], kv-permuted
  unsigned short* aO  = Vtf + MLD;

  // fused converts + weight transposes (one launch)
  prep<<<dim3(6144), dim3(256), 0, stream>>>(
      x, xb, Wo, Wob, R, Wq, Wk, Wv, RT, WqT, WkT, WvT);

  // A*T = NT(RT, W*T) = R^T W* = (W*^T R)^T   -- 64x128 tiles, grid (n=8, m=16, z=3)
  gemm_nt<true><<<dim3(8, 16, 3), dim3(256), 0, stream>>>(
      RT, WqT, WkT, WvT, (void*)AqT, (void*)AkT, (void*)AvT, 1024, 1024, 1024);
  // Q/K/V = NT(xb, A*T) -- grid (8, 64, 3) = 768 blocks = 3/CU (m97 regime)
  gemm_nt<true><<<dim3(8, 64, 3), dim3(256), 0, stream>>>(
      xb, AqT, AkT, AvT, (void*)Qb, (void*)Kb, (void*)Vb, 4096, 1024, 1024);
  // V -> V^T (f16, kv-permuted)
  tr_v<<<dim3(16, 64), dim3(256), 0, stream>>>(Vb, Vtf);
  // attention
  flash_attn<<<dim3(512), dim3(512), 0, stream>>>(Qb, Kb, Vtf, ent, aO);
  // out = NT(aO, Wob) -> fp32 -- grid (8, 64, 1) = 512 blocks = 2/CU
  gemm_nt<false><<<dim3(8, 64, 1), dim3(256), 0, stream>>>(
      aO, Wob, Wob, Wob, (void*)out, (void*)out, (void*)out, 4096, 1024, 1024);
}

// Round 8
// 194.686 us; speedup vs baseline: 1.0620x; 1.0385x over previous
//
#include <hip/hip_runtime.h>
#include <cstdint>
#include <cstddef>

// ---------- types ----------
typedef __attribute__((ext_vector_type(8))) short  bf16x8;   // MFMA bf16 A/B frag (K=32)
typedef __attribute__((ext_vector_type(8))) _Float16 f16x8;  // 16B LDS read / f16 K=32 frag
typedef __attribute__((ext_vector_type(4))) _Float16 f16x4;  // half of a K=32 A frag
typedef __attribute__((ext_vector_type(4))) float  f32x4;    // MFMA C/D frag
typedef __attribute__((ext_vector_type(4))) unsigned short u16x4;
typedef __attribute__((ext_vector_type(2))) unsigned int u32x2;

#define LOG2E 1.44269504088896340736f
#define PBIAS 6.0f   // softmax shift (cancels in normalization); keeps 2^t in f16 range

__device__ __forceinline__ unsigned short f2bf(float f) {
  unsigned int u = __builtin_bit_cast(unsigned int, f);
  u += 0x7fffu + ((u >> 16) & 1u);
  return (unsigned short)(u >> 16);
}
__device__ __forceinline__ float bf2f(unsigned short s) {
  unsigned int u = ((unsigned int)s) << 16;
  return __builtin_bit_cast(float, u);
}

// single v_exp_f32 via compiler intrinsic (hazards handled; inputs bounded here)
__device__ __forceinline__ float fast_exp2(float x) {
  return __builtin_amdgcn_exp2f(x);
}

// async global->LDS, 16B per lane (wave-uniform LDS base + lane*16)
__device__ __forceinline__ void gll16(const void* g, void* l) {
  __builtin_amdgcn_global_load_lds(
      (const __attribute__((address_space(1))) unsigned int*)g,
      (__attribute__((address_space(3))) unsigned int*)l, 16, 0, 0);
}

// ---------- fused prep: cvt x (blk<4096), cvt Wo (<5120), 4x transpose (<6144) ----------
__global__ __launch_bounds__(256) void prep(
    const float* __restrict__ x,  unsigned short* __restrict__ xb,
    const float* __restrict__ Wo, unsigned short* __restrict__ Wob,
    const float* __restrict__ R,  const float* __restrict__ Wq,
    const float* __restrict__ Wk, const float* __restrict__ Wv,
    unsigned short* __restrict__ RT,  unsigned short* __restrict__ WqT,
    unsigned short* __restrict__ WkT, unsigned short* __restrict__ WvT) {
  int bid = blockIdx.x;
  __shared__ unsigned short s[64][68];
  if (bid < 5120) {
    const float* src = bid < 4096 ? x : Wo;
    unsigned short* dst = bid < 4096 ? xb : Wob;
    int i = (bid < 4096 ? bid : bid - 4096) * 256 + threadIdx.x;
    float4 v = ((const float4*)src)[i];
    u16x4 o;
    o[0] = f2bf(v.x); o[1] = f2bf(v.y); o[2] = f2bf(v.z); o[3] = f2bf(v.w);
    ((u16x4*)dst)[i] = o;
    return;
  }
  int t = bid - 5120;
  int z = t >> 8, tile = t & 255;
  const float* in = z == 0 ? R : (z == 1 ? Wq : (z == 2 ? Wk : Wv));
  unsigned short* out = z == 0 ? RT : (z == 1 ? WqT : (z == 2 ? WkT : WvT));
  int r0 = (tile >> 4) * 64, c0 = (tile & 15) * 64;
  int tt = threadIdx.x;
  int tr = tt >> 4, tc4 = (tt & 15) * 4;
  for (int i = 0; i < 4; ++i) {
    int r = tr + i * 16;
    float4 v = *(const float4*)(in + (size_t)(r0 + r) * 1024 + c0 + tc4);
    s[r][tc4 + 0] = f2bf(v.x); s[r][tc4 + 1] = f2bf(v.y);
    s[r][tc4 + 2] = f2bf(v.z); s[r][tc4 + 3] = f2bf(v.w);
  }
  __syncthreads();
  for (int i = 0; i < 4; ++i) {
    int oc = tr + i * 16;
    u16x4 o;
    o[0] = s[tc4 + 0][oc]; o[1] = s[tc4 + 1][oc];
    o[2] = s[tc4 + 2][oc]; o[3] = s[tc4 + 3][oc];
    *(u16x4*)(out + (size_t)(c0 + oc) * 1024 + r0 + tc4) = o;
  }
}

// ---------- NT GEMM v4: C[M][N] = A[M][K]*B[N][K]^T, 64x128 tile, BK=64 ----------
// Proven __syncthreads double-buffer; 48 KB LDS -> 3 blocks/CU (m97 regime; the
// per-block vmcnt(0)-before-barrier drain overlaps other blocks' compute, m114).
// VOUT: for blockIdx.z==2 (the V slice of the QKV GEMM), the epilogue writes
// C2 as f16 [d][kv-permuted] DIRECTLY (the old tr_v kernel's output):
//   kv = m0+wm+mi*16+quad*4+i -> 32-block-local s=mi&1, q=quad, j=i
//   -> permuted slot = 8*quad + 4*(mi&1) + i  (matches tr_v's pos formula),
// so each (mi,ni) emits one aligned 8B u16x4 at
//   Vtf + d*4096 + (m0+wm+((mi>>1)<<5)) + 8*quad + 4*(mi&1),  d = n0+wn+ni*16+lo.
// This deletes the tr_v kernel + the Vb round-trip (16 MB traffic) and skips one
// bf16 quantization on V (f32->f16 direct).
template <bool BF16OUT, bool VOUT>
__global__ __launch_bounds__(256) void gemm_nt(
    const unsigned short* __restrict__ A,
    const unsigned short* __restrict__ B0, const unsigned short* __restrict__ B1,
    const unsigned short* __restrict__ B2,
    void* __restrict__ C0, void* __restrict__ C1, void* __restrict__ C2,
    int M, int N, int K) {
  const unsigned short* B = blockIdx.z == 0 ? B0 : (blockIdx.z == 1 ? B1 : B2);
  void* Cv = blockIdx.z == 0 ? C0 : (blockIdx.z == 1 ? C1 : C2);

  __shared__ unsigned short As[2][64 * 64];
  __shared__ unsigned short Bs[2][128 * 64];

  int tid = threadIdx.x, w = tid >> 6, lane = tid & 63;
  int lo = lane & 15, quad = lane >> 4;
  int m0 = blockIdx.y * 64, n0 = blockIdx.x * 128;
  int wm = (w >> 1) * 32, wn = (w & 1) * 64;

  f32x4 z4 = {0.f, 0.f, 0.f, 0.f};
  f32x4 acc[2][4];
  for (int mi = 0; mi < 2; ++mi)
    for (int ni = 0; ni < 4; ++ni) acc[mi][ni] = z4;

  int rloc = lane >> 3;
  int srcChunk = (lane & 7) ^ (rloc & 7);
  int acb = w * 2;                         // A: 4 waves cover 8 chunks (64 rows)
  int bcb = w * 4;                         // B: 4 waves cover 16 chunks (128 rows)
  const unsigned short* Ag = A + (size_t)(m0 + acb * 8 + rloc) * K + srcChunk * 8;
  const unsigned short* Bg = B + (size_t)(n0 + bcb * 8 + rloc) * K + srcChunk * 8;
  int ldsA = acb * 512 + lane * 8;
  int ldsB = bcb * 512 + lane * 8;
  int cx0 = (quad ^ (lane & 7)) * 8;
  int cx1 = ((quad + 4) ^ (lane & 7)) * 8;

  // stage k-tile 0 into buffer 0
#pragma unroll
  for (int j = 0; j < 2; ++j)
    gll16(Ag + (size_t)j * 8 * K, As[0] + ldsA + j * 512);
#pragma unroll
  for (int j = 0; j < 4; ++j)
    gll16(Bg + (size_t)j * 8 * K, Bs[0] + ldsB + j * 512);

  int nk = K >> 6;
  for (int kt = 0; kt < nk; ++kt) {
    int buf = kt & 1;
    __syncthreads();   // drains stage(kt) (issued one full compute phase ago)
    if (kt + 1 < nk) {
      int k0 = (kt + 1) << 6;
#pragma unroll
      for (int j = 0; j < 2; ++j)
        gll16(Ag + (size_t)j * 8 * K + k0, As[buf ^ 1] + ldsA + j * 512);
#pragma unroll
      for (int j = 0; j < 4; ++j)
        gll16(Bg + (size_t)j * 8 * K + k0, Bs[buf ^ 1] + ldsB + j * 512);
    }
    const unsigned short* Ab = As[buf];
    const unsigned short* Bb = Bs[buf];
#pragma unroll
    for (int ks = 0; ks < 2; ++ks) {
      int cx = ks ? cx1 : cx0;
      bf16x8 af[2], bfr[4];
#pragma unroll
      for (int mi = 0; mi < 2; ++mi)
        af[mi] = *(const bf16x8*)(Ab + (wm + mi * 16 + lo) * 64 + cx);
#pragma unroll
      for (int ni = 0; ni < 4; ++ni)
        bfr[ni] = *(const bf16x8*)(Bb + (wn + ni * 16 + lo) * 64 + cx);
#pragma unroll
      for (int mi = 0; mi < 2; ++mi)
#pragma unroll
        for (int ni = 0; ni < 4; ++ni)
          acc[mi][ni] = __builtin_amdgcn_mfma_f32_16x16x32_bf16(af[mi], bfr[ni], acc[mi][ni], 0, 0, 0);
    }
  }

  if (VOUT && blockIdx.z == 2) {
    // V slice: write f16 [d][kv-permuted] directly (tr_v's output layout)
    unsigned short* Vt = (unsigned short*)Cv;
#pragma unroll
    for (int mi = 0; mi < 2; ++mi) {
      int rb = m0 + wm + ((mi >> 1) << 5) + 8 * quad + 4 * (mi & 1);
#pragma unroll
      for (int ni = 0; ni < 4; ++ni) {
        u16x4 o;
#pragma unroll
        for (int i = 0; i < 4; ++i) {
          _Float16 h = (_Float16)acc[mi][ni][i];
          o[i] = __builtin_bit_cast(unsigned short, h);
        }
        int c = n0 + wn + ni * 16 + lo;
        *(u16x4*)(Vt + (size_t)c * 4096 + rb) = o;
      }
    }
    return;
  }

#pragma unroll
  for (int mi = 0; mi < 2; ++mi)
#pragma unroll
    for (int ni = 0; ni < 4; ++ni)
      for (int i = 0; i < 4; ++i) {
        int r = m0 + wm + mi * 16 + quad * 4 + i;
        int c = n0 + wn + ni * 16 + lo;
        if (BF16OUT)
          ((unsigned short*)Cv)[(size_t)r * N + c] = f2bf(acc[mi][ni][i]);
        else
          ((float*)Cv)[(size_t)r * N + c] = acc[mi][ni][i];
      }
}

// ---------- flash attention v13: block-internal KV split (8 waves, 2 halves) ----------
__global__ __launch_bounds__(512, 4) void flash_attn(
    const unsigned short* __restrict__ Q, const unsigned short* __restrict__ Kg_,
    const unsigned short* __restrict__ Vt, const float* __restrict__ ent,
    unsigned short* __restrict__ O) {
  int tid = threadIdx.x, w = tid >> 6, lane = tid & 63;
  int lo = lane & 15, quad = lane >> 4;
  int half = w >> 2, wl = w & 3;             // KV-half, wave-within-half

  int bid = blockIdx.x;
  int g = (bid & 7) + 8 * (bid >> 7);        // (b,h) group: id%8 fixed per group
  int qt = (bid >> 3) & 15;                  // q-tile (128 rows) within group
  int b = g >> 4, h = g & 15;
  int q0 = qt * 128;
  float scale = ent[h] * (0.125f * LOG2E);

  // 64 KB: K region [half][buf] at (half*2+buf)*4096, V region at +16384 (ushorts)
  __shared__ unsigned short lds[32768];

  // Q fragments (B-operand of S^T), scale folded in. 32 q rows/wave = 2 frag sets.
  bf16x8 aq[2][2];                             // [f][ks]
#pragma unroll
  for (int f = 0; f < 2; ++f)
#pragma unroll
    for (int ks = 0; ks < 2; ++ks) {
      uint4 v = *(const uint4*)(Q + (size_t)(b * 2048 + q0 + wl * 32 + f * 16 + lo) * 1024 +
                                h * 64 + ks * 32 + quad * 8);
      unsigned int* pv = (unsigned int*)&v;
      uint4 o; unsigned int* po = (unsigned int*)&o;
#pragma unroll
      for (int j = 0; j < 4; ++j) {
        float f0 = bf2f((unsigned short)(pv[j] & 0xffffu)) * scale;
        float f1 = bf2f((unsigned short)(pv[j] >> 16)) * scale;
        po[j] = (unsigned int)f2bf(f0) | ((unsigned int)f2bf(f1) << 16);
      }
      aq[f][ks] = *(bf16x8*)&o;
    }

  f32x4 binit = {-PBIAS, -PBIAS, -PBIAS, -PBIAS};
  f32x4 z4 = {0.f, 0.f, 0.f, 0.f};
  f32x4 acco[4][2];                            // [di][f]
#pragma unroll
  for (int di = 0; di < 4; ++di) {
    acco[di][0] = z4; acco[di][1] = z4;
  }
  float lsum0 = 0.f, lsum1 = 0.f;

  int rloc = lane >> 3;
  int srcChunk = (lane & 7) ^ (rloc & 7);
  int cb = wl * 2;                           // 4 waves/half cover 8 chunks per matrix
  const unsigned short* Kp = Kg_ + (size_t)(b * 2048 + half * 1024) * 1024 + h * 64;
  const unsigned short* Vp = Vt + (size_t)(h * 64) * 4096 + (size_t)(b * 2048 + half * 1024);
  int cx0 = (quad ^ (lane & 7)) * 8;
  int cx1 = ((quad + 4) ^ (lane & 7)) * 8;

  unsigned short* Kh = lds + half * 2 * 4096;
  unsigned short* Vh = lds + 16384 + half * 2 * 4096;

  // stage tile 0 into buffer 0 (per half)
#pragma unroll
  for (int j = 0; j < 2; ++j) {
    int c = cb + j;
    int r = c * 8 + rloc;
    gll16(Kp + (size_t)r * 1024 + srcChunk * 8, Kh + c * 512 + lane * 8);
    gll16(Vp + (size_t)r * 4096 + srcChunk * 8, Vh + c * 512 + lane * 8);
  }

  for (int it = 0; it < 16; ++it) {
    int buf = it & 1;
    __syncthreads();   // drains this tile's staging (issued one full tile ago)
    if (it + 1 < 16) {
      int kvn = (it + 1) * 64;
#pragma unroll
      for (int j = 0; j < 2; ++j) {
        int c = cb + j;
        int r = c * 8 + rloc;
        gll16(Kp + (size_t)(kvn + r) * 1024 + srcChunk * 8, Kh + (buf ^ 1) * 4096 + c * 512 + lane * 8);
        gll16(Vp + (size_t)r * 4096 + kvn + srcChunk * 8, Vh + (buf ^ 1) * 4096 + c * 512 + lane * 8);
      }
    }
    const unsigned short* Kb_ = Kh + buf * 4096;
    const unsigned short* Vb_ = Vh + buf * 4096;

    // S^T = K.Q^T : C[m=kv][n=q]; bias -PBIAS folded into the C-init (free).
    f32x4 accs[4][2];
    __builtin_amdgcn_s_setprio(1);
#pragma unroll
    for (int kt = 0; kt < 4; ++kt) {
      bf16x8 kf0 = *(const bf16x8*)(Kb_ + (kt * 16 + lo) * 64 + cx0);
      bf16x8 kf1 = *(const bf16x8*)(Kb_ + (kt * 16 + lo) * 64 + cx1);
#pragma unroll
      for (int f = 0; f < 2; ++f) {
        f32x4 a = __builtin_amdgcn_mfma_f32_16x16x32_bf16(kf0, aq[f][0], binit, 0, 0, 0);
        accs[kt][f] = __builtin_amdgcn_mfma_f32_16x16x32_bf16(kf1, aq[f][1], a, 0, 0, 0);
      }
    }
    __builtin_amdgcn_s_setprio(0);

    // P' = 2^(S^T - bias): registers hold P[q=lo][kv] == f16 A-frag layout
    f16x4 ap[4][2];
#pragma unroll
    for (int kt = 0; kt < 4; ++kt) {
#pragma unroll
      for (int f = 0; f < 2; ++f) {
        float p0 = fast_exp2(accs[kt][f][0]);
        float p1 = fast_exp2(accs[kt][f][1]);
        float p2 = fast_exp2(accs[kt][f][2]);
        float p3 = fast_exp2(accs[kt][f][3]);
        if (f == 0) lsum0 += (p0 + p1) + (p2 + p3);
        else        lsum1 += (p0 + p1) + (p2 + p3);
        u32x2 uu;
        uu[0] = __builtin_bit_cast(unsigned int, __builtin_amdgcn_cvt_pkrtz(p0, p1));
        uu[1] = __builtin_bit_cast(unsigned int, __builtin_amdgcn_cvt_pkrtz(p2, p3));
        ap[kt][f] = __builtin_bit_cast(f16x4, uu);
      }
    }

    // O += P.V via f16 16x16x32 MFMA; one b128 V read feeds both q-fragments.
    __builtin_amdgcn_s_setprio(1);
#pragma unroll
    for (int t2 = 0; t2 < 2; ++t2) {
      f16x8 a80 = __builtin_shufflevector(ap[2 * t2][0], ap[2 * t2 + 1][0], 0, 1, 2, 3, 4, 5, 6, 7);
      f16x8 a81 = __builtin_shufflevector(ap[2 * t2][1], ap[2 * t2 + 1][1], 0, 1, 2, 3, 4, 5, 6, 7);
#pragma unroll
      for (int di = 0; di < 4; ++di) {
        f16x8 bv8 = *(const f16x8*)(Vb_ + (di * 16 + lo) * 64 +
                                    (((t2 * 4 + quad) ^ (lo & 7)) << 3));
        acco[di][0] = __builtin_amdgcn_mfma_f32_16x16x32_f16(a80, bv8, acco[di][0], 0, 0, 0);
        acco[di][1] = __builtin_amdgcn_mfma_f32_16x16x32_f16(a81, bv8, acco[di][1], 0, 0, 0);
      }
    }
    __builtin_amdgcn_s_setprio(0);
  }

  // ---- combine the two KV halves (partial sums are exactly additive) ----
  __syncthreads();                         // all waves done with staging LDS
  float* cm = (float*)lds;                 // 16384 floats available
  float* base = cm + wl * 2304;            // 36 slots x 64 lanes per wl
  if (half == 1) {
#pragma unroll
    for (int di = 0; di < 4; ++di)
#pragma unroll
      for (int f = 0; f < 2; ++f)
#pragma unroll
        for (int i = 0; i < 4; ++i)
          base[(di * 8 + f * 4 + i) * 64 + lane] = acco[di][f][i];
    base[32 * 64 + lane] = lsum0;
    base[33 * 64 + lane] = lsum1;
  }
  __syncthreads();
  if (half == 1) return;

#pragma unroll
  for (int di = 0; di < 4; ++di)
#pragma unroll
    for (int f = 0; f < 2; ++f)
#pragma unroll
      for (int i = 0; i < 4; ++i)
        acco[di][f][i] += base[(di * 8 + f * 4 + i) * 64 + lane];
  lsum0 += base[32 * 64 + lane];
  lsum1 += base[33 * 64 + lane];

  // row sum for q=lo spread over quads -> 2 shuffles; per q-fragment
#pragma unroll
  for (int f = 0; f < 2; ++f) {
    float v = f == 0 ? lsum0 : lsum1;
    v += __shfl_xor(v, 16);
    v += __shfl_xor(v, 32);
    float inv = 1.0f / v;

#pragma unroll
    for (int i = 0; i < 4; ++i) {
      float invq = __shfl(inv, quad * 4 + i);
#pragma unroll
      for (int di = 0; di < 4; ++di) {
        size_t ofs = (size_t)(b * 2048 + q0 + wl * 32 + f * 16 + quad * 4 + i) * 1024 +
                     h * 64 + di * 16 + lo;
        O[ofs] = f2bf(acco[di][f][i] * invq);
      }
    }
  }
}

// ---------- launch ----------
extern "C" void kernel_launch(void* const* d_in, const int* in_sizes, int n_in,
                              void* d_out, int out_size, void* d_ws, size_t ws_size,
                              hipStream_t stream) {
  const float* x   = (const float*)d_in[0];
  const float* R   = (const float*)d_in[1];
  const float* ent = (const float*)d_in[2];
  const float* Wq  = (const float*)d_in[3];
  const float* Wk  = (const float*)d_in[4];
  const float* Wv  = (const float*)d_in[5];
  const float* Wo  = (const float*)d_in[6];
  float* out = (float*)d_out;

  const size_t MLD = (size_t)4096 * 1024;
  const size_t DD  = (size_t)1024 * 1024;
  if (ws_size < (MLD * 6 + DD * 8) * 2) return;

  unsigned short* ws  = (unsigned short*)d_ws;
  unsigned short* xb  = ws;
  unsigned short* RT  = xb + MLD;
  unsigned short* WqT = RT + DD;
  unsigned short* WkT = WqT + DD;
  unsigned short* WvT = WkT + DD;
  unsigned short* Wob = WvT + DD;
  unsigned short* AqT = Wob + DD;
  unsigned short* AkT = AqT + DD;
  unsigned short* AvT = AkT + DD;
  unsigned short* Qb  = AvT + DD;
  unsigned short* Kb  = Qb + MLD;
  unsigned short* Vb  = Kb + MLD;   // unused (V now written transposed directly)
  unsigned short* Vtf = Vb + MLD;   // V^T as f16 [1024][4096], kv-permuted
  unsigned short* aO  = Vtf + MLD;

  // fused converts + weight transposes (one launch)
  prep<<<dim3(6144), dim3(256), 0, stream>>>(
      x, xb, Wo, Wob, R, Wq, Wk, Wv, RT, WqT, WkT, WvT);

  // A*T = NT(RT, W*T) = R^T W* = (W*^T R)^T   -- 64x128 tiles, grid (n=8, m=16, z=3)
  gemm_nt<true, false><<<dim3(8, 16, 3), dim3(256), 0, stream>>>(
      RT, WqT, WkT, WvT, (void*)AqT, (void*)AkT, (void*)AvT, 1024, 1024, 1024);
  // Q/K/V = NT(xb, A*T) -- grid (8, 64, 3) = 3 blocks/CU; z=2 writes Vtf
  // (f16 [d][kv-permuted]) directly from the epilogue -- tr_v deleted.
  gemm_nt<true, true><<<dim3(8, 64, 3), dim3(256), 0, stream>>>(
      xb, AqT, AkT, AvT, (void*)Qb, (void*)Kb, (void*)Vtf, 4096, 1024, 1024);
  // attention
  flash_attn<<<dim3(512), dim3(512), 0, stream>>>(Qb, Kb, Vtf, ent, aO);
  // out = NT(aO, Wob) -> fp32 -- grid (8, 64, 1) = 2/CU
  gemm_nt<false, false><<<dim3(8, 64, 1), dim3(256), 0, stream>>>(
      aO, Wob, Wob, Wob, (void*)out, (void*)out, (void*)out, 4096, 1024, 1024);
}